// Round 6
// baseline (469.474 us; speedup 1.0000x reference)
//
#include <hip/hip_runtime.h>
#include <stdint.h>

typedef __attribute__((ext_vector_type(8))) short bf16x8;
typedef __attribute__((ext_vector_type(4))) float f32x4;

__device__ __forceinline__ float bf2f(unsigned short u) {
  union { unsigned int i; float f; } x; x.i = ((unsigned int)u) << 16; return x.f;
}
__device__ __forceinline__ unsigned short f2bf(float f) {
  union { float f; unsigned int i; } x; x.f = f;
  unsigned int i = x.i;
  return (unsigned short)((i + 0x7FFFu + ((i >> 16) & 1u)) >> 16);  // RNE
}
__device__ __forceinline__ float f16lo(unsigned int u) {
  union { unsigned short s; _Float16 h; } x; x.s = (unsigned short)(u & 0xFFFFu);
  return (float)x.h;
}
__device__ __forceinline__ float f16hi(unsigned int u) {
  union { unsigned short s; _Float16 h; } x; x.s = (unsigned short)(u >> 16);
  return (float)x.h;
}
__device__ __forceinline__ unsigned int packf16(float a, float b) {
  union { unsigned short s; _Float16 h; } x, y;
  x.h = (_Float16)a; y.h = (_Float16)b;
  return (unsigned int)x.s | ((unsigned int)y.s << 16);
}

// ---------------- CSR build ----------------

__global__ void count_kernel(const int* __restrict__ ei, int E, int* __restrict__ counts) {
  int e = blockIdx.x * blockDim.x + threadIdx.x;
  if (e < E) atomicAdd(&counts[ei[E + e]], 1);
}

__global__ void scan1_kernel(const int* __restrict__ counts, int n, int* __restrict__ bsum) {
  int i = blockIdx.x * 256 + threadIdx.x;
  int v = (i < n) ? counts[i] : 0;
  int lane = threadIdx.x & 63, w = threadIdx.x >> 6;
  for (int d = 32; d > 0; d >>= 1) v += __shfl_down(v, d, 64);
  __shared__ int ws[4];
  if (lane == 0) ws[w] = v;
  __syncthreads();
  if (threadIdx.x == 0) bsum[blockIdx.x] = ws[0] + ws[1] + ws[2] + ws[3];
}

__global__ void scan2_kernel(int* __restrict__ bsum, int G) {
  int t = threadIdx.x;
  int c = (G + 511) >> 9;
  int lo = min(t * c, G), hi = min(lo + c, G);
  int s = 0;
  for (int i = lo; i < hi; ++i) s += bsum[i];
  int lane = t & 63, w = t >> 6;
  int incl = s;
  for (int d = 1; d < 64; d <<= 1) { int u = __shfl_up(incl, d, 64); if (lane >= d) incl += u; }
  __shared__ int wsum[8];
  if (lane == 63) wsum[w] = incl;
  __syncthreads();
  int wpre = 0;
  for (int i = 0; i < w; ++i) wpre += wsum[i];
  int excl = wpre + incl - s;
  for (int i = lo; i < hi; ++i) { int v = bsum[i]; bsum[i] = excl; excl += v; }
}

__global__ void scan3_kernel(const int* __restrict__ counts, int n, const int* __restrict__ bsum,
                             int* __restrict__ offsets, int* __restrict__ cursor, int total) {
  int i = blockIdx.x * 256 + threadIdx.x;
  int v = (i < n) ? counts[i] : 0;
  int lane = threadIdx.x & 63, w = threadIdx.x >> 6;
  int incl = v;
  for (int d = 1; d < 64; d <<= 1) { int u = __shfl_up(incl, d, 64); if (lane >= d) incl += u; }
  __shared__ int wsum[4];
  if (lane == 63) wsum[w] = incl;
  __syncthreads();
  int pre = bsum[blockIdx.x];
  for (int j = 0; j < w; ++j) pre += wsum[j];
  if (i < n) {
    int excl = pre + incl - v;
    offsets[i] = excl;
    cursor[i] = excl;
  }
  if (i == 0) offsets[n] = total;
}

// fill: one 16B record per edge in CSR slot: {src_byte_offset, 3x packed fp16 basis factors}

__global__ void fill_kernel(const int* __restrict__ ei, const float* __restrict__ pseudo,
                            int E, int* __restrict__ cursor, uint4* __restrict__ recs) {
  int e = blockIdx.x * blockDim.x + threadIdx.x;
  if (e >= E) return;
  int d = ei[E + e];
  int s = ei[e];
  float2 uv = ((const float2*)pseudo)[e];
  float u = uv.x, v = uv.y;
  float b0 = 0.5f * u * u - u + 0.5f, b1 = -u * u + u + 0.5f, b2 = 0.5f * u * u;
  float c0 = 0.5f * v * v - v + 0.5f, c1 = -v * v + v + 0.5f, c2 = 0.5f * v * v;
  int p = atomicAdd(&cursor[d], 1);
  uint4 r;
  r.x = ((unsigned int)s) << 7;   // byte offset of row in bf16[64] X
  r.y = packf16(b0, b1);
  r.z = packf16(b2, c0);
  r.w = packf16(c1, c2);
  recs[p] = r;
}

// -------- weight repack, TRANSPOSED: Wt[64 cols][640 k]; k 0..575 = W.flat, 576..639 = root

__global__ void wconv_kernel(const float* __restrict__ W, const float* __restrict__ root,
                             unsigned short* __restrict__ Wt) {
  int i = blockIdx.x * blockDim.x + threadIdx.x;
  if (i >= 640 * 64) return;
  int co = i / 640, r = i % 640;
  float v = (r < 576) ? W[r * 64 + co] : root[(r - 576) * 64 + co];
  Wt[i] = f2bf(v);
}

// -------- x -> bf16

__global__ void xconv_kernel(const float4* __restrict__ x4, ushort4* __restrict__ xh4, int n4) {
  int i = blockIdx.x * blockDim.x + threadIdx.x;
  if (i < n4) {
    float4 v = x4[i];
    ushort4 o;
    o.x = f2bf(v.x); o.y = f2bf(v.y); o.z = f2bf(v.z); o.w = f2bf(v.w);
    xh4[i] = o;
  }
}

// ---------------- fused agg + GEMM ----------------
// Block 512 = 8 waves, 16 nodes/block, 2 nodes/wave. lane = channel.
// Inner loop: 8-edge batches, double-buffered records (R0/R1) so next batch's
// records load while current batch's 8 gathers are in flight.

#define SROW 648

#define LOAD8(R, jj)                                                     \
  _Pragma("unroll") for (int k = 0; k < 8; ++k) R[k] = recs[(size_t)(jj) + k];

#define PROC8(R)                                                         \
  {                                                                      \
    float xv[8];                                                         \
    _Pragma("unroll") for (int k = 0; k < 8; ++k)                        \
        xv[k] = bf2f(*(const unsigned short*)(Xb + R[k].x + laneB));     \
    _Pragma("unroll") for (int k = 0; k < 8; ++k) {                      \
      float b0 = f16lo(R[k].y), b1 = f16hi(R[k].y), b2 = f16lo(R[k].z);  \
      float c0 = f16hi(R[k].z), c1 = f16lo(R[k].w), c2 = f16hi(R[k].w);  \
      float t0 = b0 * xv[k], t1 = b1 * xv[k], t2 = b2 * xv[k];           \
      a0 += t0 * c0; a1 += t0 * c1; a2 += t0 * c2;                       \
      a3 += t1 * c0; a4 += t1 * c1; a5 += t1 * c2;                       \
      a6 += t2 * c0; a7 += t2 * c1; a8 += t2 * c2;                       \
    }                                                                    \
  }

template <bool OUTBF16>
__global__ __launch_bounds__(512) void fused_kernel(const int* __restrict__ offsets,
                                                    const uint4* __restrict__ recs,
                                                    const unsigned short* __restrict__ Xh,
                                                    const unsigned short* __restrict__ Wt,
                                                    const float* __restrict__ bias,
                                                    void* __restrict__ outv, int N) {
  __shared__ short sA[16 * SROW];
  int tid = threadIdx.x, w = tid >> 6, lane = tid & 63;
  int nodeBase = blockIdx.x * 16;
  const char* Xb = (const char*)Xh;
  unsigned int laneB = (unsigned int)lane * 2u;

#pragma unroll
  for (int t = 0; t < 2; ++t) {
    int row = w * 2 + t;
    int n = nodeBase + row;
    if (n < N) {
      int beg = __builtin_amdgcn_readfirstlane(offsets[n]);
      int end = __builtin_amdgcn_readfirstlane(offsets[n + 1]);
      float a0 = 0.f, a1 = 0.f, a2 = 0.f, a3 = 0.f, a4 = 0.f,
            a5 = 0.f, a6 = 0.f, a7 = 0.f, a8 = 0.f;
      int j = beg;
      int nfull = (end - beg) >> 3;
      uint4 R0[8], R1[8];
      if (nfull > 0) { LOAD8(R0, j); }
      int b = 0;
      while (b < nfull) {
        if (b + 1 < nfull) { LOAD8(R1, j + 8); }
        PROC8(R0);
        j += 8; ++b;
        if (b >= nfull) break;
        if (b + 1 < nfull) { LOAD8(R0, j + 8); }
        PROC8(R1);
        j += 8; ++b;
      }
      for (; j < end; ++j) {
        uint4 r = recs[j];
        float xv = bf2f(*(const unsigned short*)(Xb + r.x + laneB));
        float b0 = f16lo(r.y), b1 = f16hi(r.y), b2 = f16lo(r.z);
        float c0 = f16hi(r.z), c1 = f16lo(r.w), c2 = f16hi(r.w);
        float t0 = b0 * xv, t1 = b1 * xv, t2 = b2 * xv;
        a0 += t0 * c0; a1 += t0 * c1; a2 += t0 * c2;
        a3 += t1 * c0; a4 += t1 * c1; a5 += t1 * c2;
        a6 += t2 * c0; a7 += t2 * c1; a8 += t2 * c2;
      }
      float self = bf2f(Xh[(size_t)n * 64 + lane]);
      int rb = row * SROW;
      sA[rb + 0 * 64 + lane] = (short)f2bf(a0);
      sA[rb + 1 * 64 + lane] = (short)f2bf(a1);
      sA[rb + 2 * 64 + lane] = (short)f2bf(a2);
      sA[rb + 3 * 64 + lane] = (short)f2bf(a3);
      sA[rb + 4 * 64 + lane] = (short)f2bf(a4);
      sA[rb + 5 * 64 + lane] = (short)f2bf(a5);
      sA[rb + 6 * 64 + lane] = (short)f2bf(a6);
      sA[rb + 7 * 64 + lane] = (short)f2bf(a7);
      sA[rb + 8 * 64 + lane] = (short)f2bf(a8);
      sA[rb + 576 + lane] = (short)f2bf(self);
    }
  }
  __syncthreads();

  // ---- GEMM phase (waves 0..3): 16 block-nodes x 16 cols, K=640
  if (w < 4) {
    int r15 = lane & 15, kg = lane >> 4;
    f32x4 acc = {0.f, 0.f, 0.f, 0.f};
#pragma unroll
    for (int kk = 0; kk < 20; ++kk) {
      int kbase = kk * 32 + kg * 8;
      bf16x8 af = *(const bf16x8*)(&sA[r15 * SROW + kbase]);
      bf16x8 bfr = *(const bf16x8*)(Wt + (size_t)(w * 16 + r15) * 640 + kbase);
      acc = __builtin_amdgcn_mfma_f32_16x16x32_bf16(af, bfr, acc, 0, 0, 0);
    }
    // C/D: col = lane&15, row = (lane>>4)*4 + reg
    int col = w * 16 + r15;
    float bv = bias[col];
    int row0 = kg * 4;
#pragma unroll
    for (int r = 0; r < 4; ++r) {
      int node = nodeBase + row0 + r;
      if (node < N) {
        float val = fmaxf(acc[r] + bv, 0.f);
        size_t idx = (size_t)node * 64 + col;
        if (OUTBF16) ((unsigned short*)outv)[idx] = f2bf(val);
        else ((float*)outv)[idx] = val;
      }
    }
  }
}

// ---------------- host ----------------

extern "C" void kernel_launch(void* const* d_in, const int* in_sizes, int n_in,
                              void* d_out, int out_size, void* d_ws, size_t ws_size,
                              hipStream_t stream) {
  const float* x = (const float*)d_in[0];
  const int* ei = (const int*)d_in[1];
  const float* pseudo = (const float*)d_in[2];
  const float* W1 = (const float*)d_in[3];
  const float* root1 = (const float*)d_in[4];
  const float* b1 = (const float*)d_in[5];
  const float* W2 = (const float*)d_in[6];
  const float* root2 = (const float*)d_in[7];
  const float* b2 = (const float*)d_in[8];

  const int N = in_sizes[0] / 64;
  const int E = in_sizes[1] / 2;
  const int G = (N + 255) / 256;

  char* p = (char*)d_ws;
  auto carve = [&](size_t bytes) -> void* {
    void* r = (void*)p;
    p += (bytes + 255) & ~(size_t)255;
    return r;
  };
  int* counts = (int*)carve((size_t)N * 4);
  int* offsets = (int*)carve((size_t)(N + 1) * 4);
  int* cursor = (int*)carve((size_t)N * 4);
  int* bsum = (int*)carve((size_t)G * 4);
  uint4* recs = (uint4*)carve((size_t)E * 16);
  unsigned short* Wt1 = (unsigned short*)carve(640 * 64 * 2);
  unsigned short* Wt2 = (unsigned short*)carve(640 * 64 * 2);
  unsigned short* h = (unsigned short*)carve((size_t)N * 64 * 2);
  unsigned short* xh = (unsigned short*)carve((size_t)N * 64 * 2);
  (void)ws_size;

  hipMemsetAsync(counts, 0, (size_t)N * 4, stream);
  count_kernel<<<(E + 255) / 256, 256, 0, stream>>>(ei, E, counts);
  scan1_kernel<<<G, 256, 0, stream>>>(counts, N, bsum);
  scan2_kernel<<<1, 512, 0, stream>>>(bsum, G);
  scan3_kernel<<<G, 256, 0, stream>>>(counts, N, bsum, offsets, cursor, E);
  fill_kernel<<<(E + 255) / 256, 256, 0, stream>>>(ei, pseudo, E, cursor, recs);
  wconv_kernel<<<160, 256, 0, stream>>>(W1, root1, Wt1);
  wconv_kernel<<<160, 256, 0, stream>>>(W2, root2, Wt2);
  xconv_kernel<<<(N * 16 + 255) / 256, 256, 0, stream>>>((const float4*)x, (ushort4*)xh, N * 16);

  int FB = (N + 15) / 16;
  // layer 1: xh (bf16) -> h (bf16)
  fused_kernel<true><<<FB, 512, 0, stream>>>(offsets, recs, xh, Wt1, b1, (void*)h, N);
  // layer 2: h (bf16) -> d_out (fp32)
  fused_kernel<false><<<FB, 512, 0, stream>>>(offsets, recs, h, Wt2, b2, d_out, N);
}